// Round 9
// baseline (221.394 us; speedup 1.0000x reference)
//
#include <hip/hip_runtime.h>
#include <hip/hip_cooperative_groups.h>

namespace cg = cooperative_groups;

// GCN layer: out = scatter_add(rows, vals[:,None] * embeds[cols]) over COO.
// N=50000, E=800000, D=96 (fp32 in/out; indices int32 per harness).
//
// R5: 101us (global ranked histogram = 45us bottleneck).
// R7: two-level sort build, no global atomics: 87us.
// R8: physical reorder -> sequential accumulate reads: 76.6us. All kernels now
//     <42us; build = 5 dispatches + gaps ~ half the budget.
// R9: ONE cooperative build kernel (196 blocks, all co-resident; grid.sync
//     between phases): hist+compress -> chunk scan -> (LDS bsums scan) ->
//     scatter -> in-bin sort. 6 dispatches -> 2. Accumulate identical to R8.

#define DFEAT    96
#define BINSHIFT 8
#define BINROWS  256           // rows per bin == sort thread count
#define EPB      4096          // edges per hist/scatter block
#define CH       256           // scan chunk size (1 elem/thread)

__device__ inline unsigned bf16_rne(float x) {
    unsigned u = __float_as_uint(x);
    return (u + 0x7FFFu + ((u >> 16) & 1u)) >> 16;
}
__device__ inline float bf16_to_f32(unsigned short u) {
    return __uint_as_float((unsigned)u << 16);
}

// One cooperative kernel, phases split by grid.sync():
//  A: per-block LDS bin-histogram -> matrix[(bin,block)] ; bf16 compress (all blocks)
//  B: per-chunk exclusive scan of matrix (in place) + chunk sums
//  -: every block scans chunk sums into resident LDS (bsc)
//  C: LDS-cursor scatter into bin-ordered bucket
//  D: per-bin count/scan/cursor sort -> bucket2 (row-sorted) + nodeOffs
__global__ void build_coop_kernel(const int* __restrict__ rows, const int* __restrict__ cols,
                                  const float* __restrict__ vals, const float* __restrict__ embeds,
                                  int* __restrict__ matrix, int* __restrict__ bsums,
                                  int* __restrict__ nodeOffs,
                                  int2* __restrict__ bucket, int2* __restrict__ bucket2,
                                  unsigned short* __restrict__ ebf,
                                  int E, int B, int nbin, int nchunk, int N, int nOct, int flatN) {
    __shared__ int cnt[256];
    __shared__ int s[256];
    __shared__ int bsc[256];

    cg::grid_group grid = cg::this_grid();
    int b = blockIdx.x;
    int t = threadIdx.x;
    int base = b * EPB;
    int lim  = min(base + EPB, E);

    // ---- Phase A: histogram + compress ----
    if (b < B) {
        cnt[t] = 0;
        __syncthreads();
        for (int i = base + t; i < lim; i += 256)
            atomicAdd(&cnt[rows[i] >> BINSHIFT], 1);
        __syncthreads();
        for (int k = t; k < nbin; k += 256)
            matrix[(size_t)k * B + b] = cnt[k];
    }
    for (int j = b * 256 + t; j < nOct; j += gridDim.x * 256) {
        const float4* src = reinterpret_cast<const float4*>(embeds) + (size_t)j * 2;
        float4 f0 = src[0];
        float4 f1 = src[1];
        uint4 o;
        o.x = bf16_rne(f0.x) | (bf16_rne(f0.y) << 16);
        o.y = bf16_rne(f0.z) | (bf16_rne(f0.w) << 16);
        o.z = bf16_rne(f1.x) | (bf16_rne(f1.y) << 16);
        o.w = bf16_rne(f1.z) | (bf16_rne(f1.w) << 16);
        reinterpret_cast<uint4*>(ebf)[j] = o;
    }
    __threadfence();
    grid.sync();

    // ---- Phase B: per-chunk exclusive scan (in place) ----
    if (b < nchunk) {
        int i = b * CH + t;
        int v = (i < flatN) ? matrix[i] : 0;
        s[t] = v;
        __syncthreads();
        for (int off = 1; off < 256; off <<= 1) {
            int u = (t >= off) ? s[t - off] : 0;
            __syncthreads();
            s[t] += u;
            __syncthreads();
        }
        if (i < flatN) matrix[i] = s[t] - v;
        if (t == 255) bsums[b] = s[255];
    }
    __threadfence();
    grid.sync();

    // ---- All blocks: exclusive-scan chunk sums into resident LDS ----
    {
        int v = (t < nchunk) ? bsums[t] : 0;
        bsc[t] = v;
        __syncthreads();
        for (int off = 1; off < 256; off <<= 1) {
            int u = (t >= off) ? bsc[t - off] : 0;
            __syncthreads();
            bsc[t] += u;
            __syncthreads();
        }
        int excl = bsc[t] - v;
        __syncthreads();
        bsc[t] = excl;
        __syncthreads();
    }

    // ---- Phase C: scatter into bin-ordered bucket ----
    if (b < B) {
        for (int k = t; k < nbin; k += 256) {
            size_t flat = (size_t)k * B + b;
            cnt[k] = matrix[flat] + bsc[flat >> 8];
        }
        __syncthreads();
        for (int i = base + t; i < lim; i += 256) {
            int r = rows[i];
            int bin = r >> BINSHIFT;
            int pos = atomicAdd(&cnt[bin], 1);
            bucket[pos] = make_int2(((r & (BINROWS - 1)) << 16) | cols[i],
                                    __float_as_int(vals[i]));
        }
    }
    __threadfence();
    grid.sync();

    // ---- Phase D: in-bin sort by local row -> bucket2 + nodeOffs ----
    if (b < nbin) {
        size_t f0 = (size_t)b * B;
        int start = matrix[f0] + bsc[f0 >> 8];
        int end;
        if (b + 1 < nbin) {
            size_t f1 = (size_t)(b + 1) * B;
            end = matrix[f1] + bsc[f1 >> 8];
        } else {
            end = E;
        }

        cnt[t] = 0;
        __syncthreads();
        for (int j = start + t; j < end; j += 256)
            atomicAdd(&cnt[bucket[j].x >> 16], 1);
        __syncthreads();

        int own = cnt[t];
        s[t] = own;
        __syncthreads();
        for (int off = 1; off < 256; off <<= 1) {
            int u = (t >= off) ? s[t - off] : 0;
            __syncthreads();
            s[t] += u;
            __syncthreads();
        }
        int rowbase = start + s[t] - own;   // exclusive

        int row0 = b << BINSHIFT;
        if (row0 + t < N) nodeOffs[row0 + t] = rowbase;
        if (b == nbin - 1 && t == 0) nodeOffs[N] = E;

        cnt[t] = rowbase;                   // reuse as cursor
        __syncthreads();
        for (int j = start + t; j < end; j += 256) {
            int2 e = bucket[j];
            int pos = atomicAdd(&cnt[e.x >> 16], 1);
            bucket2[pos] = e;
        }
    }
}

// One 32-lane half-wave per node: lane l owns feats l, l+32, l+64.
// Sequential bucket2 reads, bf16 gather, 4x unrolled. No atomics. (= R8)
__global__ void accumulate_seq_kernel(const int2* __restrict__ bucket2,
                                      const int* __restrict__ nodeOffs,
                                      const unsigned short* __restrict__ ebf,
                                      float* __restrict__ out, int N) {
    int node = blockIdx.x * (blockDim.x >> 5) + (threadIdx.x >> 5);
    int lane = threadIdx.x & 31;
    if (node >= N) return;
    int start = nodeOffs[node];
    int end   = nodeOffs[node + 1];
    float a0 = 0.f, a1 = 0.f, a2 = 0.f;
    int i = start;
    for (; i + 4 <= end; i += 4) {
        int2 p0 = bucket2[i];
        int2 p1 = bucket2[i + 1];
        int2 p2 = bucket2[i + 2];
        int2 p3 = bucket2[i + 3];
        const unsigned short* e0 = ebf + (size_t)(p0.x & 0xFFFF) * DFEAT;
        const unsigned short* e1 = ebf + (size_t)(p1.x & 0xFFFF) * DFEAT;
        const unsigned short* e2 = ebf + (size_t)(p2.x & 0xFFFF) * DFEAT;
        const unsigned short* e3 = ebf + (size_t)(p3.x & 0xFFFF) * DFEAT;
        float v0 = __int_as_float(p0.y), v1 = __int_as_float(p1.y);
        float v2 = __int_as_float(p2.y), v3 = __int_as_float(p3.y);
        float x0 = bf16_to_f32(e0[lane]), y0 = bf16_to_f32(e0[lane + 32]), z0 = bf16_to_f32(e0[lane + 64]);
        float x1 = bf16_to_f32(e1[lane]), y1 = bf16_to_f32(e1[lane + 32]), z1 = bf16_to_f32(e1[lane + 64]);
        float x2 = bf16_to_f32(e2[lane]), y2 = bf16_to_f32(e2[lane + 32]), z2 = bf16_to_f32(e2[lane + 64]);
        float x3 = bf16_to_f32(e3[lane]), y3 = bf16_to_f32(e3[lane + 32]), z3 = bf16_to_f32(e3[lane + 64]);
        a0 += v0 * x0; a1 += v0 * y0; a2 += v0 * z0;
        a0 += v1 * x1; a1 += v1 * y1; a2 += v1 * z1;
        a0 += v2 * x2; a1 += v2 * y2; a2 += v2 * z2;
        a0 += v3 * x3; a1 += v3 * y3; a2 += v3 * z3;
    }
    for (; i < end; ++i) {
        int2 p = bucket2[i];
        const unsigned short* e = ebf + (size_t)(p.x & 0xFFFF) * DFEAT;
        float v = __int_as_float(p.y);
        a0 += v * bf16_to_f32(e[lane]);
        a1 += v * bf16_to_f32(e[lane + 32]);
        a2 += v * bf16_to_f32(e[lane + 64]);
    }
    float* o = out + (size_t)node * DFEAT;
    o[lane]      = a0;
    o[lane + 32] = a1;
    o[lane + 64] = a2;
}

// Last-resort fallback (R1 baseline) if sizes/ws don't fit the main path.
__global__ void gcn_scatter_atomic_kernel(const int* __restrict__ rows, const int* __restrict__ cols,
                                          const float* __restrict__ vals, const float* __restrict__ embeds,
                                          float* __restrict__ out, int n_edges) {
    long long i = (long long)blockIdx.x * blockDim.x + threadIdx.x;
    long long total = (long long)n_edges * (DFEAT / 4);
    if (i >= total) return;
    int e = (int)(i / (DFEAT / 4));
    int q = (int)(i - (long long)e * (DFEAT / 4));
    int r = rows[e], c = cols[e];
    float v = vals[e];
    const float4* emb4 = reinterpret_cast<const float4*>(embeds + (long long)c * DFEAT);
    float4 x = emb4[q];
    float* o = out + (long long)r * DFEAT + q * 4;
    atomicAdd(o + 0, v * x.x);
    atomicAdd(o + 1, v * x.y);
    atomicAdd(o + 2, v * x.z);
    atomicAdd(o + 3, v * x.w);
}

extern "C" void kernel_launch(void* const* d_in, const int* in_sizes, int n_in,
                              void* d_out, int out_size, void* d_ws, size_t ws_size,
                              hipStream_t stream) {
    const int*   rows   = (const int*)d_in[0];
    const int*   cols   = (const int*)d_in[1];
    const float* vals   = (const float*)d_in[2];
    const float* embeds = (const float*)d_in[3];
    float*       out    = (float*)d_out;

    int E = in_sizes[0];
    int N = in_sizes[3] / DFEAT;

    int nbin   = (N + BINROWS - 1) >> BINSHIFT;        // 196
    int B      = (E + EPB - 1) / EPB;                  // 196
    int flatN  = nbin * B;                             // 38,416
    int nchunk = (flatN + CH - 1) / CH;                // 151
    int G      = max(B, max(nbin, nchunk));            // 196 cooperative blocks

    // Workspace: matrix[flatN] | bsums[nchunk] | nodeOffs[N+1] | bucket[E]
    //            | bucket2[E] | ebf[N*96] (u16, 64B-aligned)
    size_t off_matrix  = 0;
    size_t off_bsums   = (off_matrix + (size_t)flatN * 4 + 15) & ~(size_t)15;
    size_t off_noffs   = (off_bsums + (size_t)nchunk * 4 + 15) & ~(size_t)15;
    size_t off_bucket  = (off_noffs + (size_t)(N + 1) * 4 + 15) & ~(size_t)15;
    size_t off_bucket2 = (off_bucket + (size_t)E * 8 + 15) & ~(size_t)15;
    size_t off_ebf     = (off_bucket2 + (size_t)E * 8 + 63) & ~(size_t)63;
    size_t need        = off_ebf + (size_t)N * DFEAT * 2;

    bool ok = (N <= 65536) && (nbin <= 256) && (nchunk <= 256) && (G <= 256) &&
              ((in_sizes[3] & 7) == 0) && (ws_size >= need);

    if (ok) {
        int*  matrix   = (int*)((char*)d_ws + off_matrix);
        int*  bsums    = (int*)((char*)d_ws + off_bsums);
        int*  nodeOffs = (int*)((char*)d_ws + off_noffs);
        int2* bucket   = (int2*)((char*)d_ws + off_bucket);
        int2* bucket2  = (int2*)((char*)d_ws + off_bucket2);
        unsigned short* ebf = (unsigned short*)((char*)d_ws + off_ebf);

        int nOct = in_sizes[3] / 8;

        void* kargs[] = {
            (void*)&rows, (void*)&cols, (void*)&vals, (void*)&embeds,
            (void*)&matrix, (void*)&bsums, (void*)&nodeOffs,
            (void*)&bucket, (void*)&bucket2, (void*)&ebf,
            (void*)&E, (void*)&B, (void*)&nbin, (void*)&nchunk,
            (void*)&N, (void*)&nOct, (void*)&flatN
        };
        hipLaunchCooperativeKernel((const void*)build_coop_kernel,
                                   dim3(G), dim3(256), kargs, 0, stream);

        int gb = (N + 7) / 8;   // 8 half-waves (nodes) per 256-thread block
        accumulate_seq_kernel<<<gb, 256, 0, stream>>>(bucket2, nodeOffs, ebf, out, N);
    } else {
        hipMemsetAsync(d_out, 0, (size_t)out_size * sizeof(float), stream);
        long long total = (long long)E * (DFEAT / 4);
        int block = 256;
        long long grid = (total + block - 1) / block;
        gcn_scatter_atomic_kernel<<<(int)grid, block, 0, stream>>>(rows, cols, vals, embeds, out, E);
    }
}

// Round 10
// 74.587 us; speedup vs baseline: 2.9683x; 2.9683x over previous
//
#include <hip/hip_runtime.h>

// GCN layer: out = scatter_add(rows, vals[:,None] * embeds[cols]) over COO.
// N=50000, E=800000, D=96 (fp32 in/out; indices int32 per harness).
//
// R7: two-level sort build, no global atomics: 87us.
// R8: physical reorder -> sequential accumulate: 76.6us.
// R9: cooperative fusion FAILED (196-block grid -> 1 wave/SIMD -> 181us kernel).
//     Lesson: grid.sync forces min-phase parallelism on all phases.
// R10: back to R8 multi-kernel; fuse sort INTO accumulate at 32-row bins
//     (1563 blocks): per-chunk LDS count/scan/cursor sort + half-wave register
//     accumulate from sorted LDS. bucket2 + nodeOffs + 1 dispatch eliminated.

#define DFEAT    96
#define BINSHIFT 5
#define BINROWS  32            // rows per bin
#define MAXBIN   2048          // LDS hist/cursor capacity (8KB)
#define EPB      4096          // edges per hist/scatter block
#define SCT      1024          // scan width
#define CAP      1024          // edges per sortaccum chunk (8KB LDS)

__device__ inline unsigned bf16_rne(float x) {
    unsigned u = __float_as_uint(x);
    return (u + 0x7FFFu + ((u >> 16) & 1u)) >> 16;
}
__device__ inline float bf16_to_f32(unsigned short u) {
    return __uint_as_float((unsigned)u << 16);
}

// Blocks [0,B): LDS histogram of this block's EPB edges over nbin bins,
//   written to matrix[bin*B + block] (bin-major for the flat scan).
// Blocks [B,...): fp32 -> bf16 embeds compression (8 floats/thread).
__global__ void hist_bin_compress_kernel(const int* __restrict__ rows,
                                         int* __restrict__ matrix, int E, int B, int nbin,
                                         const float* __restrict__ embeds,
                                         unsigned short* __restrict__ ebf, int nOct) {
    __shared__ int cnt[MAXBIN];
    int b = blockIdx.x;
    if (b < B) {
        for (int k = threadIdx.x; k < nbin; k += blockDim.x) cnt[k] = 0;
        __syncthreads();
        int base = b * EPB;
        int lim  = min(base + EPB, E);
        for (int i = base + threadIdx.x; i < lim; i += blockDim.x)
            atomicAdd(&cnt[rows[i] >> BINSHIFT], 1);
        __syncthreads();
        for (int k = threadIdx.x; k < nbin; k += blockDim.x)
            matrix[(size_t)k * B + b] = cnt[k];
    } else {
        int j = (b - B) * blockDim.x + threadIdx.x;
        if (j < nOct) {
            const float4* src = reinterpret_cast<const float4*>(embeds) + (size_t)j * 2;
            float4 f0 = src[0];
            float4 f1 = src[1];
            uint4 o;
            o.x = bf16_rne(f0.x) | (bf16_rne(f0.y) << 16);
            o.y = bf16_rne(f0.z) | (bf16_rne(f0.w) << 16);
            o.z = bf16_rne(f1.x) | (bf16_rne(f1.y) << 16);
            o.w = bf16_rne(f1.z) | (bf16_rne(f1.w) << 16);
            reinterpret_cast<uint4*>(ebf)[j] = o;
        }
    }
}

// In-place per-block exclusive scan (one elem/thread, coalesced); block sums out.
// Result is partial — consumers add bsums[flatIdx >> 10] themselves.
__global__ void scan1024_kernel(int* __restrict__ data, int* __restrict__ bsums, int n) {
    __shared__ int s[SCT];
    int t = threadIdx.x;
    int i = blockIdx.x * SCT + t;
    int v = (i < n) ? data[i] : 0;
    s[t] = v;
    __syncthreads();
    for (int off = 1; off < SCT; off <<= 1) {
        int u = (t >= off) ? s[t - off] : 0;
        __syncthreads();
        s[t] += u;
        __syncthreads();
    }
    if (i < n) data[i] = s[t] - v;
    if (t == SCT - 1) bsums[blockIdx.x] = s[t];
}

// Single-block in-place exclusive scan of the block sums (nb <= SCT).
__global__ void scan_sums1024_kernel(int* __restrict__ bsums, int nb) {
    __shared__ int s[SCT];
    int t = threadIdx.x;
    int v = (t < nb) ? bsums[t] : 0;
    s[t] = v;
    __syncthreads();
    for (int off = 1; off < SCT; off <<= 1) {
        int u = (t >= off) ? s[t - off] : 0;
        __syncthreads();
        s[t] += u;
        __syncthreads();
    }
    if (t < nb) bsums[t] = s[t] - v;
}

__device__ inline int scanned_at(const int* __restrict__ matrixScan,
                                 const int* __restrict__ bsums, long long flatIdx) {
    return matrixScan[flatIdx] + bsums[flatIdx >> 10];
}

// Scatter edges to row-bin buckets. Cursor bases from the scanned matrix
// (+bsums fixup); within-block ranks via LDS atomics only.
// entry: (lrow<<16 | col, val) with lrow in [0,32).
__global__ void scatter_bin_kernel(const int* __restrict__ rows, const int* __restrict__ cols,
                                   const float* __restrict__ vals,
                                   const int* __restrict__ matrixScan,
                                   const int* __restrict__ bsums,
                                   int2* __restrict__ bucket, int E, int B, int nbin) {
    __shared__ int cur[MAXBIN];
    int b = blockIdx.x;
    for (int k = threadIdx.x; k < nbin; k += blockDim.x)
        cur[k] = scanned_at(matrixScan, bsums, (long long)k * B + b);
    __syncthreads();
    int base = b * EPB;
    int lim  = min(base + EPB, E);
    for (int i = base + threadIdx.x; i < lim; i += blockDim.x) {
        int r = rows[i];
        int bin = r >> BINSHIFT;
        int pos = atomicAdd(&cur[bin], 1);
        bucket[pos] = make_int2(((r & (BINROWS - 1)) << 16) | cols[i],
                                __float_as_int(vals[i]));
    }
}

// One 256-thread block per 32-row bin. Per 1024-edge chunk: edges -> registers
// (coalesced), LDS count over 32 row-counters, 32-wide LDS scan, cursor-scatter
// into sorted LDS, then each half-wave accumulates its 4 rows from LDS
// (broadcast) with register accumulators persisting across chunks.
__global__ void sortaccum_kernel(const int2* __restrict__ bucket,
                                 const int* __restrict__ matrixScan,
                                 const int* __restrict__ bsums,
                                 const unsigned short* __restrict__ ebf,
                                 float* __restrict__ out, int E, int B, int nbin, int N) {
    __shared__ int2 sorted[CAP];     // 8 KB
    __shared__ int cnt[BINROWS];
    __shared__ int segs[BINROWS];
    __shared__ int cur[BINROWS];
    __shared__ int s32[BINROWS];

    int bin = blockIdx.x;
    int t = threadIdx.x;
    int hw = t >> 5;                 // 8 half-waves
    int lane = t & 31;

    int start = scanned_at(matrixScan, bsums, (long long)bin * B);
    int end   = (bin + 1 < nbin) ? scanned_at(matrixScan, bsums, (long long)(bin + 1) * B) : E;

    float acc[4][3];
    #pragma unroll
    for (int rr = 0; rr < 4; ++rr) { acc[rr][0] = 0.f; acc[rr][1] = 0.f; acc[rr][2] = 0.f; }

    for (int cs = start; cs < end; cs += CAP) {
        int m = min(CAP, end - cs);

        if (t < BINROWS) cnt[t] = 0;
        __syncthreads();

        // Load chunk edges into registers + LDS count.
        int2 ee[4];
        #pragma unroll
        for (int k = 0; k < 4; ++k) {
            int j = t + k * 256;
            if (j < m) {
                ee[k] = bucket[cs + j];
                atomicAdd(&cnt[ee[k].x >> 16], 1);
            }
        }
        __syncthreads();

        // Exclusive scan of the 32 counters.
        if (t < BINROWS) s32[t] = cnt[t];
        __syncthreads();
        for (int off = 1; off < BINROWS; off <<= 1) {
            int u = (t < BINROWS && t >= off) ? s32[t - off] : 0;
            __syncthreads();
            if (t < BINROWS) s32[t] += u;
            __syncthreads();
        }
        if (t < BINROWS) {
            int ex = s32[t] - cnt[t];
            segs[t] = ex;
            cur[t]  = ex;
        }
        __syncthreads();

        // Cursor-scatter into sorted LDS.
        #pragma unroll
        for (int k = 0; k < 4; ++k) {
            int j = t + k * 256;
            if (j < m) {
                int pos = atomicAdd(&cur[ee[k].x >> 16], 1);
                sorted[pos] = ee[k];
            }
        }
        __syncthreads();

        // Accumulate: half-wave hw owns rows hw*4 .. hw*4+3.
        #pragma unroll
        for (int rr = 0; rr < 4; ++rr) {
            int r = hw * 4 + rr;
            int j  = segs[r];
            int je = segs[r] + cnt[r];
            for (; j + 4 <= je; j += 4) {
                int2 p0 = sorted[j];
                int2 p1 = sorted[j + 1];
                int2 p2 = sorted[j + 2];
                int2 p3 = sorted[j + 3];
                const unsigned short* e0 = ebf + (size_t)(p0.x & 0xFFFF) * DFEAT;
                const unsigned short* e1 = ebf + (size_t)(p1.x & 0xFFFF) * DFEAT;
                const unsigned short* e2 = ebf + (size_t)(p2.x & 0xFFFF) * DFEAT;
                const unsigned short* e3 = ebf + (size_t)(p3.x & 0xFFFF) * DFEAT;
                float v0 = __int_as_float(p0.y), v1 = __int_as_float(p1.y);
                float v2 = __int_as_float(p2.y), v3 = __int_as_float(p3.y);
                float x0 = bf16_to_f32(e0[lane]), y0 = bf16_to_f32(e0[lane + 32]), z0 = bf16_to_f32(e0[lane + 64]);
                float x1 = bf16_to_f32(e1[lane]), y1 = bf16_to_f32(e1[lane + 32]), z1 = bf16_to_f32(e1[lane + 64]);
                float x2 = bf16_to_f32(e2[lane]), y2 = bf16_to_f32(e2[lane + 32]), z2 = bf16_to_f32(e2[lane + 64]);
                float x3 = bf16_to_f32(e3[lane]), y3 = bf16_to_f32(e3[lane + 32]), z3 = bf16_to_f32(e3[lane + 64]);
                acc[rr][0] += v0 * x0 + v1 * x1;
                acc[rr][1] += v0 * y0 + v1 * y1;
                acc[rr][2] += v0 * z0 + v1 * z1;
                acc[rr][0] += v2 * x2 + v3 * x3;
                acc[rr][1] += v2 * y2 + v3 * y3;
                acc[rr][2] += v2 * z2 + v3 * z3;
            }
            for (; j < je; ++j) {
                int2 p = sorted[j];
                const unsigned short* e = ebf + (size_t)(p.x & 0xFFFF) * DFEAT;
                float v = __int_as_float(p.y);
                acc[rr][0] += v * bf16_to_f32(e[lane]);
                acc[rr][1] += v * bf16_to_f32(e[lane + 32]);
                acc[rr][2] += v * bf16_to_f32(e[lane + 64]);
            }
        }
        __syncthreads();   // protect cnt/sorted before next chunk
    }

    // Write out this bin's rows.
    int row0 = bin << BINSHIFT;
    #pragma unroll
    for (int rr = 0; rr < 4; ++rr) {
        int row = row0 + hw * 4 + rr;
        if (row < N) {
            float* o = out + (size_t)row * DFEAT;
            o[lane]      = acc[rr][0];
            o[lane + 32] = acc[rr][1];
            o[lane + 64] = acc[rr][2];
        }
    }
}

// Last-resort fallback (R1 baseline) if sizes/ws don't fit the main path.
__global__ void gcn_scatter_atomic_kernel(const int* __restrict__ rows, const int* __restrict__ cols,
                                          const float* __restrict__ vals, const float* __restrict__ embeds,
                                          float* __restrict__ out, int n_edges) {
    long long i = (long long)blockIdx.x * blockDim.x + threadIdx.x;
    long long total = (long long)n_edges * (DFEAT / 4);
    if (i >= total) return;
    int e = (int)(i / (DFEAT / 4));
    int q = (int)(i - (long long)e * (DFEAT / 4));
    int r = rows[e], c = cols[e];
    float v = vals[e];
    const float4* emb4 = reinterpret_cast<const float4*>(embeds + (long long)c * DFEAT);
    float4 x = emb4[q];
    float* o = out + (long long)r * DFEAT + q * 4;
    atomicAdd(o + 0, v * x.x);
    atomicAdd(o + 1, v * x.y);
    atomicAdd(o + 2, v * x.z);
    atomicAdd(o + 3, v * x.w);
}

extern "C" void kernel_launch(void* const* d_in, const int* in_sizes, int n_in,
                              void* d_out, int out_size, void* d_ws, size_t ws_size,
                              hipStream_t stream) {
    const int*   rows   = (const int*)d_in[0];
    const int*   cols   = (const int*)d_in[1];
    const float* vals   = (const float*)d_in[2];
    const float* embeds = (const float*)d_in[3];
    float*       out    = (float*)d_out;

    int E = in_sizes[0];
    int N = in_sizes[3] / DFEAT;

    int nbin  = (N + BINROWS - 1) >> BINSHIFT;        // 1563
    int B     = (E + EPB - 1) / EPB;                  // 196
    long long flatN = (long long)nbin * B;            // 306,348
    int SB    = (int)((flatN + SCT - 1) / SCT);       // 300

    // Workspace: matrix[flatN] | bsums[SB] | bucket[E] (int2) | ebf[N*96] (u16)
    size_t off_matrix = 0;
    size_t off_bsums  = (off_matrix + (size_t)flatN * 4 + 15) & ~(size_t)15;
    size_t off_bucket = (off_bsums + (size_t)SB * 4 + 15) & ~(size_t)15;
    size_t off_ebf    = (off_bucket + (size_t)E * 8 + 63) & ~(size_t)63;
    size_t need       = off_ebf + (size_t)N * DFEAT * 2;

    bool ok = (N <= 65536) && (nbin <= MAXBIN) && (SB <= SCT) &&
              ((in_sizes[3] & 7) == 0) && (ws_size >= need);

    if (ok) {
        int*  matrix = (int*)((char*)d_ws + off_matrix);
        int*  bsums  = (int*)((char*)d_ws + off_bsums);
        int2* bucket = (int2*)((char*)d_ws + off_bucket);
        unsigned short* ebf = (unsigned short*)((char*)d_ws + off_ebf);

        int nOct = in_sizes[3] / 8;
        int cb   = (nOct + 255) / 256;

        hist_bin_compress_kernel<<<B + cb, 256, 0, stream>>>(
            rows, matrix, E, B, nbin, embeds, ebf, nOct);

        scan1024_kernel<<<SB, SCT, 0, stream>>>(matrix, bsums, (int)flatN);
        scan_sums1024_kernel<<<1, SCT, 0, stream>>>(bsums, SB);

        scatter_bin_kernel<<<B, 256, 0, stream>>>(rows, cols, vals, matrix, bsums,
                                                  bucket, E, B, nbin);

        sortaccum_kernel<<<nbin, 256, 0, stream>>>(bucket, matrix, bsums, ebf, out,
                                                   E, B, nbin, N);
    } else {
        hipMemsetAsync(d_out, 0, (size_t)out_size * sizeof(float), stream);
        long long total = (long long)E * (DFEAT / 4);
        int block = 256;
        long long grid = (total + block - 1) / block;
        gcn_scatter_atomic_kernel<<<(int)grid, block, 0, stream>>>(rows, cols, vals, embeds, out, E);
    }
}